// Round 7
// baseline (320.031 us; speedup 1.0000x reference)
//
#include <hip/hip_runtime.h>
#include <hip/hip_bf16.h>
#include <math.h>
#include <stdint.h>

// ArcFace loss via MX-fp8 (e4m3, identity scales) MFMA GEMM + fused
// fixed-max softmax. B=2048, D=512, C=50000. Output: scalar mean NLL (f32).
//
// R7: LDS-pipe-bound fix. A-fragments direct from global (L2-resident via
// XCD-affinity) with EXPLICIT one-iter-ahead register prefetch (R6 failed
// because launch_bounds(256,4) left no regs to prefetch -> vmcnt(0) chains).
// B double-buffered in LDS, one barrier per K-iter. LDS traffic per block
// halves (384KB -> 192KB); A rides the parallel TA/L1/L2 path.
//
// Numerics: logits = 30*cos in [-30,30] -> fixed max 30, plain sums:
//   lse = 30 + log(sum_c exp(l_c - 30)); label logit recomputed exactly in
//   fp32 at finalize, so fp8 error only perturbs the softmax denominator.

#define B_ROWS    2048
#define D_DIM     512
#define C_CLASSES 50000
#define C_PAD     50048            // 391 * 128
#define NCHUNK    391
#define CPX       49               // chunks per XCD (8*49=392 slots, 1 unused)
#define ARC_MARGIN 0.3f
#define ARC_SCALE  30.0f
#define ARC_EPS    1e-12f
#define K_LOG2E_S  43.2808512f     // 30 * log2(e)

// workspace layout (bytes)
#define OFF_WQ    0u               // 50048*512 = 25,624,576
#define OFF_EMBQ  25624576u        // 2048*512  =  1,048,576
#define OFF_WINV  26673152u        // 50000*4   =    200,000
#define OFF_EINV  26873152u        // 2048*4    =      8,192
#define OFF_PART  26881344u        // 2048*391*4 = 3,203,072
// total ~30.1 MB

typedef __attribute__((ext_vector_type(8))) int   i32x8;
typedef __attribute__((ext_vector_type(4))) int   i32x4;
typedef __attribute__((ext_vector_type(4))) float f32x4;

typedef __attribute__((address_space(1))) const unsigned int g_u32;
typedef __attribute__((address_space(3))) unsigned int       l_u32;

__device__ __forceinline__ void gload_lds16(const void* g, void* l) {
    // dest is wave-uniform LDS base; HW writes lane i at base + i*16
    g_u32* gp = (g_u32*)(uintptr_t)g;
    l_u32* lp = (l_u32*)(uintptr_t)l;
    __builtin_amdgcn_global_load_lds(gp, lp, 16, 0, 0);
}

// ---------------- prep: rows -> normalized e4m3 + inverse norms ----------------
// gw < C_PAD: weight row (pad rows zero-filled); else: embedding row.
__global__ __launch_bounds__(256) void k_prep(const float* __restrict__ emb,
                                              const float* __restrict__ weight,
                                              uint8_t* __restrict__ embq,
                                              uint8_t* __restrict__ wq,
                                              float* __restrict__ einv,
                                              float* __restrict__ winv,
                                              float* __restrict__ out) {
    if (blockIdx.x == 0 && threadIdx.x == 0) out[0] = 0.f;  // zero for k_fin atomics
    int gw   = (blockIdx.x * blockDim.x + threadIdx.x) >> 6;   // one wave per row
    int lane = threadIdx.x & 63;
    const float* src;
    uint8_t* dst;
    float* invout;
    if (gw < C_PAD) {
        if (gw >= C_CLASSES) {                // zero-fill pad classes
            *(int2*)(wq + (size_t)gw * D_DIM + lane * 8) = make_int2(0, 0);
            return;
        }
        src = weight + (size_t)gw * D_DIM;
        dst = wq + (size_t)gw * D_DIM;
        invout = winv + gw;
    } else {
        int row = gw - C_PAD;
        src = emb + (size_t)row * D_DIM;
        dst = embq + (size_t)row * D_DIM;
        invout = einv + row;
    }
    const float4* r4 = (const float4*)src;
    float4 v0 = r4[lane * 2];
    float4 v1 = r4[lane * 2 + 1];
    float s = v0.x*v0.x + v0.y*v0.y + v0.z*v0.z + v0.w*v0.w
            + v1.x*v1.x + v1.y*v1.y + v1.z*v1.z + v1.w*v1.w;
    #pragma unroll
    for (int off = 32; off; off >>= 1) s += __shfl_xor(s, off);
    float r = 1.0f / fmaxf(sqrtf(s), ARC_EPS);
    if (lane == 0) *invout = r;
    int p0 = __builtin_amdgcn_cvt_pk_fp8_f32(v0.x * r, v0.y * r, 0, false);
    p0     = __builtin_amdgcn_cvt_pk_fp8_f32(v0.z * r, v0.w * r, p0, true);
    int p1 = __builtin_amdgcn_cvt_pk_fp8_f32(v1.x * r, v1.y * r, 0, false);
    p1     = __builtin_amdgcn_cvt_pk_fp8_f32(v1.z * r, v1.w * r, p1, true);
    *(int2*)(dst + lane * 8) = make_int2(p0, p1);
}

struct TrueT  { static constexpr bool value = true;  };
struct FalseT { static constexpr bool value = false; };

// ---------------- GEMM (MX-fp8, identity scales) + softmax partials -----------
__global__ __launch_bounds__(256, 3) void k_gemm(const uint8_t* __restrict__ embq,
                                                 const uint8_t* __restrict__ wq,
                                                 float* __restrict__ partials) {
    // B LDS layout per 16KB buffer: 8 col-blocks of 16 cols; within block
    // [kc 0..7][col 0..15] 16B cells. global_load_lds lane order == layout
    // order; frag ds_read_b128: 16 consecutive lanes read 256 contiguous B.
    __shared__ __align__(16) uint8_t B_s[2][16384];
    __shared__ float Red[128][2];

    const int tid    = threadIdx.x;
    const int w      = tid >> 6;        // wave 0..3
    const int lane   = tid & 63;
    const int lanelo = lane & 15;
    const int quad   = lane >> 4;
    const int wrow0  = (w >> 1) * 64;   // wave's row base in tile
    const int wcol0  = (w & 1) * 64;    // wave's col base in tile

    // XCD-affinity decode: round-robin dispatch -> xcd = id & 7 (heuristic).
    // XCD k owns chunks [k*49, k*49+48]; B slice (3.1 MB) + A (1 MB) fit L2.
    const int id    = blockIdx.x;
    const int xcd   = id & 7;
    const int s_    = id >> 3;          // 0..783
    const int rb_   = s_ & 15;          // row-block
    const int chunk = xcd * CPX + (s_ >> 4);
    if (chunk >= NCHUNK) return;        // 8 pad slots
    const int b0 = rb_ * 128;
    const int n0 = chunk * 128;

    const uint8_t* Abase = embq + (size_t)b0 * D_DIM;
    const uint8_t* Bbase = wq   + (size_t)n0 * D_DIM;

    f32x4 acc[4][4];
    #pragma unroll
    for (int i = 0; i < 4; ++i)
        #pragma unroll
        for (int j = 0; j < 4; ++j)
            acc[i][j] = (f32x4){0.f, 0.f, 0.f, 0.f};

    const int srow = lane & 15;
    const int skc  = lane >> 4;

    auto stageB = [&](int kt, uint8_t* dst) {
        const int k0 = kt * 128;
        #pragma unroll
        for (int t = 0; t < 2; ++t) {
            const int rb = w * 2 + t;           // col-block 0..7
            #pragma unroll
            for (int h = 0; h < 2; ++h) {
                const int kc = h * 4 + skc;     // 0..7
                gload_lds16(Bbase + (size_t)(rb * 16 + srow) * D_DIM + k0 + kc * 16,
                            dst + rb * 2048 + h * 1024);
            }
        }
    };

    // A-fragment direct from global: row = b0+((w>>1)*4+i)*16+lanelo,
    // k = kt*128 + quad*32 .. +31  (layout HW-verified in R6, absmax 0)
    const uint8_t* Arow = Abase + (size_t)((w >> 1) * 64 + lanelo) * D_DIM
                                + quad * 32;
    auto loadA = [&](i32x8* dst, int kt) {
        #pragma unroll
        for (int i = 0; i < 4; ++i) {
            const uint8_t* p = Arow + (size_t)i * 16 * D_DIM + kt * 128;
            i32x4 lo = *(const i32x4*)p;
            i32x4 hi = *(const i32x4*)(p + 16);
            dst[i] = (i32x8){lo[0], lo[1], lo[2], lo[3],
                             hi[0], hi[1], hi[2], hi[3]};
        }
    };

    i32x8 Af[2][4];                     // ping-pong A-fragment buffers
    loadA(Af[0], 0);                    // prefetch kt=0
    stageB(0, B_s[0]);

    #pragma unroll
    for (int kt = 0; kt < 4; ++kt) {
        uint8_t* cur = B_s[kt & 1];
        __syncthreads();                 // B tile kt resident (vmcnt drained)
        if (kt < 3) stageB(kt + 1, B_s[(kt & 1) ^ 1]);  // flies under MFMA

        i32x8 bfr[4];
        #pragma unroll
        for (int j = 0; j < 4; ++j) {
            const int rb = (w & 1) * 4 + j;
            i32x4 lo = *(const i32x4*)&cur[rb * 2048 + quad * 512 + lanelo * 16];
            i32x4 hi = *(const i32x4*)&cur[rb * 2048 + quad * 512 + 256 + lanelo * 16];
            bfr[j] = (i32x8){lo[0], lo[1], lo[2], lo[3], hi[0], hi[1], hi[2], hi[3]};
        }

        if (kt < 3) loadA(Af[(kt & 1) ^ 1], kt + 1);   // prefetch next A

        const i32x8* a = Af[kt & 1];
        #pragma unroll
        for (int i = 0; i < 4; ++i)
            #pragma unroll
            for (int j = 0; j < 4; ++j)
                acc[i][j] = __builtin_amdgcn_mfma_scale_f32_16x16x128_f8f6f4(
                    a[i], bfr[j], acc[i][j],
                    0, 0,          // cbsz=fp8(e4m3), blgp=fp8(e4m3)
                    0, 127,        // scale A: identity (E8M0 127 = 1.0)
                    0, 127);       // scale B: identity
    }

    // epilogue: C/D layout col=lane&15, row=quad*4+reg (shape-determined).
    // Reduce-scatter butterfly over the 16 lanelo lanes: 15 shfl total;
    // lane lanelo ends with full sum for row-index == lanelo. (R6-verified)
    float s[16];
    auto fill = [&](auto maskTag) {
        constexpr bool MASK = decltype(maskTag)::value;
        #pragma unroll
        for (int i = 0; i < 4; ++i) {
            #pragma unroll
            for (int reg = 0; reg < 4; ++reg) {
                float s4 = 0.f;
                #pragma unroll
                for (int j = 0; j < 4; ++j) {
                    float t = __builtin_amdgcn_exp2f(
                        fmaf(acc[i][j][reg], K_LOG2E_S, -K_LOG2E_S));
                    if (MASK) {
                        int c = n0 + wcol0 + j * 16 + lanelo;
                        if (c >= C_CLASSES) t = 0.f;
                    }
                    s4 += t;
                }
                s[i * 4 + reg] = s4;
            }
        }
    };
    if (chunk == NCHUNK - 1) fill(TrueT{}); else fill(FalseT{});

    #pragma unroll
    for (int m = 8; m >= 1; m >>= 1) {
        bool upper = (lanelo & m) != 0;
        #pragma unroll
        for (int t = 0; t < m; ++t) {
            float lo = s[t], hi = s[t + m];
            float send = upper ? lo : hi;
            float recv = __shfl_xor(send, m);
            s[t] = (upper ? hi : lo) + recv;
        }
    }
    {
        int row = wrow0 + (lanelo >> 2) * 16 + quad * 4 + (lanelo & 3);
        Red[row][w & 1] = s[0];
    }
    __syncthreads();

    if (tid < 128)
        partials[(size_t)(b0 + tid) * NCHUNK + chunk] = Red[tid][0] + Red[tid][1];
}

// -------- finalize: exact label logit + partial sum -> atomic mean NLL --------
__global__ __launch_bounds__(256) void k_fin(const float* __restrict__ emb,
                                             const float* __restrict__ weight,
                                             const float* __restrict__ einv,
                                             const float* __restrict__ winv,
                                             const int* __restrict__ labels,
                                             const float* __restrict__ partials,
                                             float* __restrict__ out) {
    __shared__ float sm[4];
    int widx = threadIdx.x >> 6;
    int b    = blockIdx.x * 4 + widx;    // one wave per row
    int lane = threadIdx.x & 63;
    int label = labels[b];

    const float4* e  = (const float4*)(emb + (size_t)b * D_DIM);
    const float4* wt = (const float4*)(weight + (size_t)label * D_DIM);
    float4 e0 = e[lane],  e1 = e[lane + 64];
    float4 w0 = wt[lane], w1 = wt[lane + 64];
    float dot = e0.x*w0.x + e0.y*w0.y + e0.z*w0.z + e0.w*w0.w
              + e1.x*w1.x + e1.y*w1.y + e1.z*w1.z + e1.w*w1.w;
    float ls = 0.f;
    for (int idx = lane; idx < NCHUNK; idx += 64)
        ls += partials[(size_t)b * NCHUNK + idx];
    #pragma unroll
    for (int off = 32; off; off >>= 1) {
        dot += __shfl_xor(dot, off);
        ls  += __shfl_xor(ls, off);
    }

    float cosv   = dot * einv[b] * winv[label];
    float l_orig = ARC_SCALE * cosv;
    float l_adj  = ARC_SCALE * (cosv - ARC_MARGIN);

    // swap (fp8-accumulated) label term for exact margin-adjusted one
    float s_adj = ls - __expf(l_orig - ARC_SCALE) + __expf(l_adj - ARC_SCALE);
    float v = ARC_SCALE + logf(s_adj) - l_adj;
    if (lane == 0) sm[widx] = v;
    __syncthreads();
    if (threadIdx.x == 0)
        atomicAdd(out, (sm[0] + sm[1] + sm[2] + sm[3]) * (1.0f / (float)B_ROWS));
}

extern "C" void kernel_launch(void* const* d_in, const int* in_sizes, int n_in,
                              void* d_out, int out_size, void* d_ws, size_t ws_size,
                              hipStream_t stream) {
    const float* emb    = (const float*)d_in[0];   // (2048, 512) f32
    const int*   labels = (const int*)d_in[1];     // (2048,)
    const float* weight = (const float*)d_in[2];   // (50000, 512) f32
    float* out = (float*)d_out;

    char* ws = (char*)d_ws;
    uint8_t* wq    = (uint8_t*)(ws + OFF_WQ);
    uint8_t* embq  = (uint8_t*)(ws + OFF_EMBQ);
    float* winv     = (float*)(ws + OFF_WINV);
    float* einv     = (float*)(ws + OFF_EINV);
    float* partials = (float*)(ws + OFF_PART);

    k_prep<<<(C_PAD + B_ROWS) / 4, 256, 0, stream>>>(emb, weight, embq, wq,
                                                     einv, winv, out);

    k_gemm<<<8 * CPX * 16, 256, 0, stream>>>(embq, wq, partials);

    k_fin<<<B_ROWS / 4, 256, 0, stream>>>(emb, weight, einv, winv, labels,
                                          partials, out);
}

// Round 8
// 302.158 us; speedup vs baseline: 1.0591x; 1.0591x over previous
//
#include <hip/hip_runtime.h>
#include <hip/hip_bf16.h>
#include <math.h>
#include <stdint.h>

// ArcFace loss via MX-fp8 (e4m3, identity scales) MFMA GEMM + fused
// fixed-max softmax. B=2048, D=512, C=50000. Output: scalar mean NLL (f32).
//
// R8: the K-loop is LDS-PORT-BOUND (R2-R5 all sit at 65-83 B/cyc/CU of LDS
// traffic = the ds_read_b128 ceiling). Cut LDS bytes 384->192 KB/block:
//   - A-fragments direct from global (L2-resident; layout verified R6/R7)
//     with a 2-pair ping-pong (32 regs max -- R7's 64-reg dbuf spilled).
//   - B via LDS, double-buffered, ONE barrier per kt.
//   - launch_bounds(256,3): acc64+A32+Bfrag32+addr~12 = ~140 < 170, no spill.
//
// Numerics: logits = 30*cos in [-30,30] -> fixed max 30, plain sums:
//   lse = 30 + log(sum_c exp(l_c - 30)); label logit recomputed exactly in
//   fp32 at finalize, so fp8 error only perturbs the softmax denominator.

#define B_ROWS    2048
#define D_DIM     512
#define C_CLASSES 50000
#define C_PAD     50048            // 391 * 128
#define NCHUNK    391
#define CPX       49               // chunks per XCD (8*49=392 slots, 1 unused)
#define ARC_MARGIN 0.3f
#define ARC_SCALE  30.0f
#define ARC_EPS    1e-12f
#define K_LOG2E_S  43.2808512f     // 30 * log2(e)

// workspace layout (bytes)
#define OFF_WQ    0u               // 50048*512 = 25,624,576
#define OFF_EMBQ  25624576u        // 2048*512  =  1,048,576
#define OFF_WINV  26673152u        // 50000*4   =    200,000
#define OFF_EINV  26873152u        // 2048*4    =      8,192
#define OFF_PART  26881344u        // 2048*391*4 = 3,203,072
// total ~30.1 MB

typedef __attribute__((ext_vector_type(8))) int   i32x8;
typedef __attribute__((ext_vector_type(4))) int   i32x4;
typedef __attribute__((ext_vector_type(4))) float f32x4;

typedef __attribute__((address_space(1))) const unsigned int g_u32;
typedef __attribute__((address_space(3))) unsigned int       l_u32;

__device__ __forceinline__ void gload_lds16(const void* g, void* l) {
    // dest is wave-uniform LDS base; HW writes lane i at base + i*16
    g_u32* gp = (g_u32*)(uintptr_t)g;
    l_u32* lp = (l_u32*)(uintptr_t)l;
    __builtin_amdgcn_global_load_lds(gp, lp, 16, 0, 0);
}

// ---------------- prep: rows -> normalized e4m3 + inverse norms ----------------
// gw < C_PAD: weight row (pad rows zero-filled); else: embedding row.
__global__ __launch_bounds__(256) void k_prep(const float* __restrict__ emb,
                                              const float* __restrict__ weight,
                                              uint8_t* __restrict__ embq,
                                              uint8_t* __restrict__ wq,
                                              float* __restrict__ einv,
                                              float* __restrict__ winv,
                                              float* __restrict__ out) {
    if (blockIdx.x == 0 && threadIdx.x == 0) out[0] = 0.f;  // zero for k_fin atomics
    int gw   = (blockIdx.x * blockDim.x + threadIdx.x) >> 6;   // one wave per row
    int lane = threadIdx.x & 63;
    const float* src;
    uint8_t* dst;
    float* invout;
    if (gw < C_PAD) {
        if (gw >= C_CLASSES) {                // zero-fill pad classes
            *(int2*)(wq + (size_t)gw * D_DIM + lane * 8) = make_int2(0, 0);
            return;
        }
        src = weight + (size_t)gw * D_DIM;
        dst = wq + (size_t)gw * D_DIM;
        invout = winv + gw;
    } else {
        int row = gw - C_PAD;
        src = emb + (size_t)row * D_DIM;
        dst = embq + (size_t)row * D_DIM;
        invout = einv + row;
    }
    const float4* r4 = (const float4*)src;
    float4 v0 = r4[lane * 2];
    float4 v1 = r4[lane * 2 + 1];
    float s = v0.x*v0.x + v0.y*v0.y + v0.z*v0.z + v0.w*v0.w
            + v1.x*v1.x + v1.y*v1.y + v1.z*v1.z + v1.w*v1.w;
    #pragma unroll
    for (int off = 32; off; off >>= 1) s += __shfl_xor(s, off);
    float r = 1.0f / fmaxf(sqrtf(s), ARC_EPS);
    if (lane == 0) *invout = r;
    int p0 = __builtin_amdgcn_cvt_pk_fp8_f32(v0.x * r, v0.y * r, 0, false);
    p0     = __builtin_amdgcn_cvt_pk_fp8_f32(v0.z * r, v0.w * r, p0, true);
    int p1 = __builtin_amdgcn_cvt_pk_fp8_f32(v1.x * r, v1.y * r, 0, false);
    p1     = __builtin_amdgcn_cvt_pk_fp8_f32(v1.z * r, v1.w * r, p1, true);
    *(int2*)(dst + lane * 8) = make_int2(p0, p1);
}

struct TrueT  { static constexpr bool value = true;  };
struct FalseT { static constexpr bool value = false; };

// ---------------- GEMM (MX-fp8, identity scales) + softmax partials -----------
__global__ __launch_bounds__(256, 3) void k_gemm(const uint8_t* __restrict__ embq,
                                                 const uint8_t* __restrict__ wq,
                                                 float* __restrict__ partials) {
    // B LDS layout per 16KB buffer: 8 col-blocks of 16 cols; within block
    // [kc 0..7][col 0..15] 16B cells. global_load_lds lane order == layout
    // order; frag ds_read_b128: 16 consecutive lanes read 256 contiguous B.
    __shared__ __align__(16) uint8_t B_s[2][16384];
    __shared__ float Red[128][2];

    const int tid    = threadIdx.x;
    const int w      = tid >> 6;        // wave 0..3
    const int lane   = tid & 63;
    const int lanelo = lane & 15;
    const int quad   = lane >> 4;
    const int wrow0  = (w >> 1) * 64;   // wave's row base in tile
    const int wcol0  = (w & 1) * 64;    // wave's col base in tile

    // XCD-affinity decode: round-robin dispatch -> xcd = id & 7 (heuristic).
    // XCD k owns chunks [k*49, k*49+48]; B slice (3.1 MB) + A (1 MB) fit L2.
    const int id    = blockIdx.x;
    const int xcd   = id & 7;
    const int s_    = id >> 3;          // 0..783
    const int rb_   = s_ & 15;          // row-block
    const int chunk = xcd * CPX + (s_ >> 4);
    if (chunk >= NCHUNK) return;        // 8 pad slots
    const int b0 = rb_ * 128;
    const int n0 = chunk * 128;

    const uint8_t* Abase = embq + (size_t)b0 * D_DIM;
    const uint8_t* Bbase = wq   + (size_t)n0 * D_DIM;

    f32x4 acc[4][4];
    #pragma unroll
    for (int i = 0; i < 4; ++i)
        #pragma unroll
        for (int j = 0; j < 4; ++j)
            acc[i][j] = (f32x4){0.f, 0.f, 0.f, 0.f};

    const int srow = lane & 15;
    const int skc  = lane >> 4;

    auto stageB = [&](int kt, uint8_t* dst) {
        const int k0 = kt * 128;
        #pragma unroll
        for (int t = 0; t < 2; ++t) {
            const int rb = w * 2 + t;           // col-block 0..7
            #pragma unroll
            for (int h = 0; h < 2; ++h) {
                const int kc = h * 4 + skc;     // 0..7
                gload_lds16(Bbase + (size_t)(rb * 16 + srow) * D_DIM + k0 + kc * 16,
                            dst + rb * 2048 + h * 1024);
            }
        }
    };

    // A-fragment direct from global: row = b0+((w>>1)*4+i)*16+lanelo,
    // k = kt*128 + quad*32 .. +31  (layout HW-verified in R6/R7, absmax 0)
    const uint8_t* Arow = Abase + (size_t)((w >> 1) * 64 + lanelo) * D_DIM
                                + quad * 32;
    auto loadA1 = [&](int i, int kt) -> i32x8 {
        const uint8_t* p = Arow + (size_t)i * 16 * D_DIM + kt * 128;
        i32x4 lo = *(const i32x4*)p;
        i32x4 hi = *(const i32x4*)(p + 16);
        return (i32x8){lo[0], lo[1], lo[2], lo[3],
                       hi[0], hi[1], hi[2], hi[3]};
    };

    // ping-pong A pairs: at most 32 A regs live (R7's 64-reg dbuf spilled)
    i32x8 aP0 = loadA1(0, 0);
    i32x8 aP1 = loadA1(1, 0);
    stageB(0, B_s[0]);

    #pragma unroll
    for (int kt = 0; kt < 4; ++kt) {
        uint8_t* cur = B_s[kt & 1];
        __syncthreads();                 // B tile kt resident (vmcnt drained)
        if (kt < 3) stageB(kt + 1, B_s[(kt & 1) ^ 1]);  // flies under MFMA

        i32x8 bfr[4];
        #pragma unroll
        for (int j = 0; j < 4; ++j) {
            const int rb = (w & 1) * 4 + j;
            i32x4 lo = *(const i32x4*)&cur[rb * 2048 + quad * 512 + lanelo * 16];
            i32x4 hi = *(const i32x4*)&cur[rb * 2048 + quad * 512 + 256 + lanelo * 16];
            bfr[j] = (i32x8){lo[0], lo[1], lo[2], lo[3], hi[0], hi[1], hi[2], hi[3]};
        }

        // second A pair of this kt, in flight under the first MFMA burst
        i32x8 aQ0 = loadA1(2, kt);
        i32x8 aQ1 = loadA1(3, kt);

        #pragma unroll
        for (int j = 0; j < 4; ++j)
            acc[0][j] = __builtin_amdgcn_mfma_scale_f32_16x16x128_f8f6f4(
                aP0, bfr[j], acc[0][j], 0, 0, 0, 127, 0, 127);
        #pragma unroll
        for (int j = 0; j < 4; ++j)
            acc[1][j] = __builtin_amdgcn_mfma_scale_f32_16x16x128_f8f6f4(
                aP1, bfr[j], acc[1][j], 0, 0, 0, 127, 0, 127);

        if (kt < 3) {                    // first A pair of next kt
            aP0 = loadA1(0, kt + 1);
            aP1 = loadA1(1, kt + 1);
        }

        #pragma unroll
        for (int j = 0; j < 4; ++j)
            acc[2][j] = __builtin_amdgcn_mfma_scale_f32_16x16x128_f8f6f4(
                aQ0, bfr[j], acc[2][j], 0, 0, 0, 127, 0, 127);
        #pragma unroll
        for (int j = 0; j < 4; ++j)
            acc[3][j] = __builtin_amdgcn_mfma_scale_f32_16x16x128_f8f6f4(
                aQ1, bfr[j], acc[3][j], 0, 0, 0, 127, 0, 127);
    }

    // epilogue: C/D layout col=lane&15, row=quad*4+reg (shape-determined).
    // Reduce-scatter butterfly over the 16 lanelo lanes: 15 shfl total;
    // lane lanelo ends with full sum for row-index == lanelo. (R6/R7-verified)
    float s[16];
    auto fill = [&](auto maskTag) {
        constexpr bool MASK = decltype(maskTag)::value;
        #pragma unroll
        for (int i = 0; i < 4; ++i) {
            #pragma unroll
            for (int reg = 0; reg < 4; ++reg) {
                float s4 = 0.f;
                #pragma unroll
                for (int j = 0; j < 4; ++j) {
                    float t = __builtin_amdgcn_exp2f(
                        fmaf(acc[i][j][reg], K_LOG2E_S, -K_LOG2E_S));
                    if (MASK) {
                        int c = n0 + wcol0 + j * 16 + lanelo;
                        if (c >= C_CLASSES) t = 0.f;
                    }
                    s4 += t;
                }
                s[i * 4 + reg] = s4;
            }
        }
    };
    if (chunk == NCHUNK - 1) fill(TrueT{}); else fill(FalseT{});

    #pragma unroll
    for (int m = 8; m >= 1; m >>= 1) {
        bool upper = (lanelo & m) != 0;
        #pragma unroll
        for (int t = 0; t < m; ++t) {
            float lo = s[t], hi = s[t + m];
            float send = upper ? lo : hi;
            float recv = __shfl_xor(send, m);
            s[t] = (upper ? hi : lo) + recv;
        }
    }
    {
        int row = wrow0 + (lanelo >> 2) * 16 + quad * 4 + (lanelo & 3);
        Red[row][w & 1] = s[0];
    }
    __syncthreads();

    if (tid < 128)
        partials[(size_t)(b0 + tid) * NCHUNK + chunk] = Red[tid][0] + Red[tid][1];
}

// -------- finalize: exact label logit + partial sum -> atomic mean NLL --------
__global__ __launch_bounds__(256) void k_fin(const float* __restrict__ emb,
                                             const float* __restrict__ weight,
                                             const float* __restrict__ einv,
                                             const float* __restrict__ winv,
                                             const int* __restrict__ labels,
                                             const float* __restrict__ partials,
                                             float* __restrict__ out) {
    __shared__ float sm[4];
    int widx = threadIdx.x >> 6;
    int b    = blockIdx.x * 4 + widx;    // one wave per row
    int lane = threadIdx.x & 63;
    int label = labels[b];

    const float4* e  = (const float4*)(emb + (size_t)b * D_DIM);
    const float4* wt = (const float4*)(weight + (size_t)label * D_DIM);
    float4 e0 = e[lane],  e1 = e[lane + 64];
    float4 w0 = wt[lane], w1 = wt[lane + 64];
    float dot = e0.x*w0.x + e0.y*w0.y + e0.z*w0.z + e0.w*w0.w
              + e1.x*w1.x + e1.y*w1.y + e1.z*w1.z + e1.w*w1.w;
    float ls = 0.f;
    for (int idx = lane; idx < NCHUNK; idx += 64)
        ls += partials[(size_t)b * NCHUNK + idx];
    #pragma unroll
    for (int off = 32; off; off >>= 1) {
        dot += __shfl_xor(dot, off);
        ls  += __shfl_xor(ls, off);
    }

    float cosv   = dot * einv[b] * winv[label];
    float l_orig = ARC_SCALE * cosv;
    float l_adj  = ARC_SCALE * (cosv - ARC_MARGIN);

    // swap (fp8-accumulated) label term for exact margin-adjusted one
    float s_adj = ls - __expf(l_orig - ARC_SCALE) + __expf(l_adj - ARC_SCALE);
    float v = ARC_SCALE + logf(s_adj) - l_adj;
    if (lane == 0) sm[widx] = v;
    __syncthreads();
    if (threadIdx.x == 0)
        atomicAdd(out, (sm[0] + sm[1] + sm[2] + sm[3]) * (1.0f / (float)B_ROWS));
}

extern "C" void kernel_launch(void* const* d_in, const int* in_sizes, int n_in,
                              void* d_out, int out_size, void* d_ws, size_t ws_size,
                              hipStream_t stream) {
    const float* emb    = (const float*)d_in[0];   // (2048, 512) f32
    const int*   labels = (const int*)d_in[1];     // (2048,)
    const float* weight = (const float*)d_in[2];   // (50000, 512) f32
    float* out = (float*)d_out;

    char* ws = (char*)d_ws;
    uint8_t* wq    = (uint8_t*)(ws + OFF_WQ);
    uint8_t* embq  = (uint8_t*)(ws + OFF_EMBQ);
    float* winv     = (float*)(ws + OFF_WINV);
    float* einv     = (float*)(ws + OFF_EINV);
    float* partials = (float*)(ws + OFF_PART);

    k_prep<<<(C_PAD + B_ROWS) / 4, 256, 0, stream>>>(emb, weight, embq, wq,
                                                     einv, winv, out);

    k_gemm<<<8 * CPX * 16, 256, 0, stream>>>(embq, wq, partials);

    k_fin<<<B_ROWS / 4, 256, 0, stream>>>(emb, weight, einv, winv, labels,
                                          partials, out);
}

// Round 9
// 289.994 us; speedup vs baseline: 1.1036x; 1.0419x over previous
//
#include <hip/hip_runtime.h>
#include <hip/hip_bf16.h>
#include <math.h>
#include <stdint.h>

// ArcFace loss via MX-fp8 (e4m3, identity scales) MFMA GEMM + fused
// fixed-max softmax. B=2048, D=512, C=50000. Output: scalar mean NLL (f32).
//
// R9: back to the proven R5 K-loop (A+B LDS-staged, 2 barriers/kt; R8's
// A-direct died on the in-order vmcnt queue: reg-loads issued after
// global_load_lds staging must wait for the staging to land). New: raise
// occupancy 3->4 waves/SIMD via __launch_bounds__(256,4) + pressure-shaped
// inner loop (B frags read one-at-a-time interleaved with their MFMA quad:
// live set ~116 regs < 128) + R6's 15-shfl reduce-scatter epilogue.
//
// Numerics: logits = 30*cos in [-30,30] -> fixed max 30, plain sums:
//   lse = 30 + log(sum_c exp(l_c - 30)); label logit recomputed exactly in
//   fp32 at finalize, so fp8 error only perturbs the softmax denominator.

#define B_ROWS    2048
#define D_DIM     512
#define C_CLASSES 50000
#define C_PAD     50048            // 391 * 128
#define NCHUNK    391
#define CPX       49               // chunks per XCD (8*49=392 slots, 1 unused)
#define ARC_MARGIN 0.3f
#define ARC_SCALE  30.0f
#define ARC_EPS    1e-12f
#define K_LOG2E_S  43.2808512f     // 30 * log2(e)

// workspace layout (bytes)
#define OFF_WQ    0u               // 50048*512 = 25,624,576
#define OFF_EMBQ  25624576u        // 2048*512  =  1,048,576
#define OFF_WINV  26673152u        // 50000*4   =    200,000
#define OFF_EINV  26873152u        // 2048*4    =      8,192
#define OFF_PART  26881344u        // 2048*391*4 = 3,203,072
// total ~30.1 MB

typedef __attribute__((ext_vector_type(8))) int   i32x8;
typedef __attribute__((ext_vector_type(4))) int   i32x4;
typedef __attribute__((ext_vector_type(4))) float f32x4;

typedef __attribute__((address_space(1))) const unsigned int g_u32;
typedef __attribute__((address_space(3))) unsigned int       l_u32;

__device__ __forceinline__ void gload_lds16(const void* g, void* l) {
    // dest is wave-uniform LDS base; HW writes lane i at base + i*16
    g_u32* gp = (g_u32*)(uintptr_t)g;
    l_u32* lp = (l_u32*)(uintptr_t)l;
    __builtin_amdgcn_global_load_lds(gp, lp, 16, 0, 0);
}

// ---------------- prep: rows -> normalized e4m3 + inverse norms ----------------
// gw < C_PAD: weight row (pad rows zero-filled); else: embedding row.
__global__ __launch_bounds__(256) void k_prep(const float* __restrict__ emb,
                                              const float* __restrict__ weight,
                                              uint8_t* __restrict__ embq,
                                              uint8_t* __restrict__ wq,
                                              float* __restrict__ einv,
                                              float* __restrict__ winv,
                                              float* __restrict__ out) {
    if (blockIdx.x == 0 && threadIdx.x == 0) out[0] = 0.f;  // zero for k_fin atomics
    int gw   = (blockIdx.x * blockDim.x + threadIdx.x) >> 6;   // one wave per row
    int lane = threadIdx.x & 63;
    const float* src;
    uint8_t* dst;
    float* invout;
    if (gw < C_PAD) {
        if (gw >= C_CLASSES) {                // zero-fill pad classes
            *(int2*)(wq + (size_t)gw * D_DIM + lane * 8) = make_int2(0, 0);
            return;
        }
        src = weight + (size_t)gw * D_DIM;
        dst = wq + (size_t)gw * D_DIM;
        invout = winv + gw;
    } else {
        int row = gw - C_PAD;
        src = emb + (size_t)row * D_DIM;
        dst = embq + (size_t)row * D_DIM;
        invout = einv + row;
    }
    const float4* r4 = (const float4*)src;
    float4 v0 = r4[lane * 2];
    float4 v1 = r4[lane * 2 + 1];
    float s = v0.x*v0.x + v0.y*v0.y + v0.z*v0.z + v0.w*v0.w
            + v1.x*v1.x + v1.y*v1.y + v1.z*v1.z + v1.w*v1.w;
    #pragma unroll
    for (int off = 32; off; off >>= 1) s += __shfl_xor(s, off);
    float r = 1.0f / fmaxf(sqrtf(s), ARC_EPS);
    if (lane == 0) *invout = r;
    int p0 = __builtin_amdgcn_cvt_pk_fp8_f32(v0.x * r, v0.y * r, 0, false);
    p0     = __builtin_amdgcn_cvt_pk_fp8_f32(v0.z * r, v0.w * r, p0, true);
    int p1 = __builtin_amdgcn_cvt_pk_fp8_f32(v1.x * r, v1.y * r, 0, false);
    p1     = __builtin_amdgcn_cvt_pk_fp8_f32(v1.z * r, v1.w * r, p1, true);
    *(int2*)(dst + lane * 8) = make_int2(p0, p1);
}

struct TrueT  { static constexpr bool value = true;  };
struct FalseT { static constexpr bool value = false; };

// ---------------- GEMM (MX-fp8, identity scales) + softmax partials -----------
__global__ __launch_bounds__(256, 4) void k_gemm(const uint8_t* __restrict__ embq,
                                                 const uint8_t* __restrict__ wq,
                                                 float* __restrict__ partials) {
    // LDS tile layout (per 16KB tile): 8 row-blocks of 16 rows; within block
    // [kc 0..7][row 0..15] 16B cells. global_load_lds lane order == layout
    // order; frag ds_read_b128: 16 consecutive lanes read 256 contiguous B.
    __shared__ __align__(16) uint8_t A_s[16384];
    __shared__ __align__(16) uint8_t B_s[16384];
    __shared__ float Red[128][2];

    const int tid    = threadIdx.x;
    const int w      = tid >> 6;        // wave 0..3
    const int lane   = tid & 63;
    const int lanelo = lane & 15;
    const int quad   = lane >> 4;
    const int wrow0  = (w >> 1) * 64;   // wave's row base in tile
    const int wcol0  = (w & 1) * 64;    // wave's col base in tile

    // XCD-affinity decode: round-robin dispatch -> xcd = id & 7 (heuristic).
    // XCD k owns chunks [k*49, k*49+48]; B slice (3.1 MB) + A (1 MB) fit L2.
    const int id    = blockIdx.x;
    const int xcd   = id & 7;
    const int s_    = id >> 3;          // 0..783
    const int rb_   = s_ & 15;          // row-block
    const int chunk = xcd * CPX + (s_ >> 4);
    if (chunk >= NCHUNK) return;        // 8 pad slots
    const int b0 = rb_ * 128;
    const int n0 = chunk * 128;

    const uint8_t* Abase = embq + (size_t)b0 * D_DIM;
    const uint8_t* Bbase = wq   + (size_t)n0 * D_DIM;

    f32x4 acc[4][4];
    #pragma unroll
    for (int i = 0; i < 4; ++i)
        #pragma unroll
        for (int j = 0; j < 4; ++j)
            acc[i][j] = (f32x4){0.f, 0.f, 0.f, 0.f};

    const int srow = lane & 15;
    const int skc  = lane >> 4;

    auto stage = [&](int kt) {
        const int k0 = kt * 128;
        #pragma unroll
        for (int t = 0; t < 2; ++t) {
            const int rb = w * 2 + t;           // row/col-block 0..7
            #pragma unroll
            for (int h = 0; h < 2; ++h) {
                const int kc = h * 4 + skc;     // 0..7
                gload_lds16(Abase + (size_t)(rb * 16 + srow) * D_DIM + k0 + kc * 16,
                            &A_s[rb * 2048 + h * 1024]);
                gload_lds16(Bbase + (size_t)(rb * 16 + srow) * D_DIM + k0 + kc * 16,
                            &B_s[rb * 2048 + h * 1024]);
            }
        }
    };

    stage(0);
    #pragma unroll
    for (int kt = 0; kt < 4; ++kt) {
        __syncthreads();                 // (a) tile kt resident (vmcnt drained)

        // A fragments (32 regs live)
        i32x8 af[4];
        #pragma unroll
        for (int i = 0; i < 4; ++i) {
            const int rb = (w >> 1) * 4 + i;
            i32x4 lo = *(const i32x4*)&A_s[rb * 2048 + quad * 512 + lanelo * 16];
            i32x4 hi = *(const i32x4*)&A_s[rb * 2048 + quad * 512 + 256 + lanelo * 16];
            af[i] = (i32x8){lo[0], lo[1], lo[2], lo[3], hi[0], hi[1], hi[2], hi[3]};
        }
        // B fragments one-at-a-time, interleaved with their MFMA quad:
        // keeps live set ~116 regs so 4 waves/SIMD fit (the R5 version kept
        // all 4 B frags live -> 148 regs -> 3 waves/SIMD).
        #pragma unroll
        for (int j = 0; j < 4; ++j) {
            const int rb = (w & 1) * 4 + j;
            i32x4 lo = *(const i32x4*)&B_s[rb * 2048 + quad * 512 + lanelo * 16];
            i32x4 hi = *(const i32x4*)&B_s[rb * 2048 + quad * 512 + 256 + lanelo * 16];
            i32x8 bf = (i32x8){lo[0], lo[1], lo[2], lo[3], hi[0], hi[1], hi[2], hi[3]};
            #pragma unroll
            for (int i = 0; i < 4; ++i)
                acc[i][j] = __builtin_amdgcn_mfma_scale_f32_16x16x128_f8f6f4(
                    af[i], bf, acc[i][j],
                    0, 0,          // cbsz=fp8(e4m3), blgp=fp8(e4m3)
                    0, 127,        // scale A: identity (E8M0 127 = 1.0)
                    0, 127);       // scale B: identity
        }
        __syncthreads();                 // (b) all LDS reads of kt done
        if (kt < 3) stage(kt + 1);       // refill same buffers
    }

    // epilogue: C/D layout col=lane&15, row=quad*4+reg (shape-determined).
    // Reduce-scatter butterfly over the 16 lanelo lanes: 15 shfl total;
    // lane lanelo ends with full sum for row-index == lanelo. (R6-R8 verified)
    float s[16];
    auto fill = [&](auto maskTag) {
        constexpr bool MASK = decltype(maskTag)::value;
        #pragma unroll
        for (int i = 0; i < 4; ++i) {
            #pragma unroll
            for (int reg = 0; reg < 4; ++reg) {
                float s4 = 0.f;
                #pragma unroll
                for (int j = 0; j < 4; ++j) {
                    float t = __builtin_amdgcn_exp2f(
                        fmaf(acc[i][j][reg], K_LOG2E_S, -K_LOG2E_S));
                    if (MASK) {
                        int c = n0 + wcol0 + j * 16 + lanelo;
                        if (c >= C_CLASSES) t = 0.f;
                    }
                    s4 += t;
                }
                s[i * 4 + reg] = s4;
            }
        }
    };
    if (chunk == NCHUNK - 1) fill(TrueT{}); else fill(FalseT{});

    #pragma unroll
    for (int m = 8; m >= 1; m >>= 1) {
        bool upper = (lanelo & m) != 0;
        #pragma unroll
        for (int t = 0; t < m; ++t) {
            float lo = s[t], hi = s[t + m];
            float send = upper ? lo : hi;
            float recv = __shfl_xor(send, m);
            s[t] = (upper ? hi : lo) + recv;
        }
    }
    {
        int row = wrow0 + (lanelo >> 2) * 16 + quad * 4 + (lanelo & 3);
        Red[row][w & 1] = s[0];
    }
    __syncthreads();

    if (tid < 128)
        partials[(size_t)(b0 + tid) * NCHUNK + chunk] = Red[tid][0] + Red[tid][1];
}

// -------- finalize: exact label logit + partial sum -> atomic mean NLL --------
__global__ __launch_bounds__(256) void k_fin(const float* __restrict__ emb,
                                             const float* __restrict__ weight,
                                             const float* __restrict__ einv,
                                             const float* __restrict__ winv,
                                             const int* __restrict__ labels,
                                             const float* __restrict__ partials,
                                             float* __restrict__ out) {
    __shared__ float sm[4];
    int widx = threadIdx.x >> 6;
    int b    = blockIdx.x * 4 + widx;    // one wave per row
    int lane = threadIdx.x & 63;
    int label = labels[b];

    const float4* e  = (const float4*)(emb + (size_t)b * D_DIM);
    const float4* wt = (const float4*)(weight + (size_t)label * D_DIM);
    float4 e0 = e[lane],  e1 = e[lane + 64];
    float4 w0 = wt[lane], w1 = wt[lane + 64];
    float dot = e0.x*w0.x + e0.y*w0.y + e0.z*w0.z + e0.w*w0.w
              + e1.x*w1.x + e1.y*w1.y + e1.z*w1.z + e1.w*w1.w;
    float ls = 0.f;
    for (int idx = lane; idx < NCHUNK; idx += 64)
        ls += partials[(size_t)b * NCHUNK + idx];
    #pragma unroll
    for (int off = 32; off; off >>= 1) {
        dot += __shfl_xor(dot, off);
        ls  += __shfl_xor(ls, off);
    }

    float cosv   = dot * einv[b] * winv[label];
    float l_orig = ARC_SCALE * cosv;
    float l_adj  = ARC_SCALE * (cosv - ARC_MARGIN);

    // swap (fp8-accumulated) label term for exact margin-adjusted one
    float s_adj = ls - __expf(l_orig - ARC_SCALE) + __expf(l_adj - ARC_SCALE);
    float v = ARC_SCALE + logf(s_adj) - l_adj;
    if (lane == 0) sm[widx] = v;
    __syncthreads();
    if (threadIdx.x == 0)
        atomicAdd(out, (sm[0] + sm[1] + sm[2] + sm[3]) * (1.0f / (float)B_ROWS));
}

extern "C" void kernel_launch(void* const* d_in, const int* in_sizes, int n_in,
                              void* d_out, int out_size, void* d_ws, size_t ws_size,
                              hipStream_t stream) {
    const float* emb    = (const float*)d_in[0];   // (2048, 512) f32
    const int*   labels = (const int*)d_in[1];     // (2048,)
    const float* weight = (const float*)d_in[2];   // (50000, 512) f32
    float* out = (float*)d_out;

    char* ws = (char*)d_ws;
    uint8_t* wq    = (uint8_t*)(ws + OFF_WQ);
    uint8_t* embq  = (uint8_t*)(ws + OFF_EMBQ);
    float* winv     = (float*)(ws + OFF_WINV);
    float* einv     = (float*)(ws + OFF_EINV);
    float* partials = (float*)(ws + OFF_PART);

    k_prep<<<(C_PAD + B_ROWS) / 4, 256, 0, stream>>>(emb, weight, embq, wq,
                                                     einv, winv, out);

    k_gemm<<<8 * CPX * 16, 256, 0, stream>>>(embq, wq, partials);

    k_fin<<<B_ROWS / 4, 256, 0, stream>>>(emb, weight, einv, winv, labels,
                                          partials, out);
}